// Round 23
// baseline (66.340 us; speedup 1.0000x reference)
//
#include <hip/hip_runtime.h>

// Point-splat renderer, round 23: STASH-FREE binsort (re-project pass 2) +
// R22 thread-per-run paint.
//
//  R22 post-mortem: binsort stuck ~40us. Remaining defect: 31KB LDS stash
//  caps occupancy (46KB -> 3 blk/CU) and round-trips every point through
//  LDS. Fix: drop the stash; pass 2 RE-PROJECTS (positions 48MB fits the
//  256MB L3 -> second read is L3-resident; projection is cheap, VALU was
//  15%). LDS 14KB -> 4 blk/CU = 32 waves/CU (100%). Re-projection is
//  bit-identical (same code/inputs, deterministic FP).
//
//  Kernel 1 (binsort, 512x512): pass1 project (float4x3) + LDS histogram;
//  exclusive scan of raw counts; publish (base<<16|count) tile-major
//  histG[t*NB+b]; pass2 re-project + scatter via LDS cursors -> dense
//  (lp<<22|idx) stores into the block's private region.
//  Kernel 2 (paint, 1024x512): thread tid walks run (region tid, tile t),
//  exact count; LDS atomicMax(idx+1); gather colors; CHW store.
//  winner = max index is order-free -> deterministic.
//
// Inputs: d_in[0] positions (N*3 f32), d_in[1] colors (N*3 f32),
//         d_in[2] camera_pose (16 f32), d_in[3] intrinsics (9 f32),
//         d_in[4] H (1 int), d_in[5] W (1 int)
// Output: (1,3,H,W) f32 flat.

#define NB      512            // binsort blocks / regions
#define TB      512            // threads per block (binsort & paint)
#define NT      1024           // 32x32 grid of 32x32-px tiles
#define PPB_MAX 65536          // no stash: generous ppb cap (fits 16-bit run counts? see note)
#define IMGW    1024
#define IMGHW   (1024 * 1024)

__host__ __device__ __forceinline__ unsigned align8u(unsigned x) {
    return (x + 7u) & ~7u;
}

// Shared projection body: computes packed pixel (or sentinel) for 4 points.
#define PROJ4(PV, A, B, C)                                                   \
    {                                                                        \
        float xs0 = A.x, ys0 = A.y, zs0 = A.z;                               \
        float xs1 = A.w, ys1 = B.x, zs1 = B.y;                               \
        float xs2 = B.z, ys2 = B.w, zs2 = C.x;                               \
        float xs3 = C.y, ys3 = C.z, zs3 = C.w;                               \
        PROJ1(PV[0], xs0, ys0, zs0)                                          \
        PROJ1(PV[1], xs1, ys1, zs1)                                          \
        PROJ1(PV[2], xs2, ys2, zs2)                                          \
        PROJ1(PV[3], xs3, ys3, zs3)                                          \
    }

#define PROJ1(P, PX, PY, PZ)                                                 \
    {                                                                        \
        float x = r00 * PX + r01 * PY + r02 * PZ + t0;                       \
        float y = r10 * PX + r11 * PY + r12 * PZ + t1;                       \
        float z = r20 * PX + r21 * PY + r22 * PZ + t2;                       \
        float u = fx * x / z + cx;                                           \
        float v = fy * y / z + cy;                                           \
        int xi = (int)u;   /* trunc == numpy astype(int32) */                \
        int yi = (int)v;                                                     \
        P = 0xFFFFFFFFu;                                                     \
        if (xi >= 0 && xi < IMGW && yi >= 0 && yi < IMGW)                    \
            P = ((unsigned)yi << 10) | (unsigned)xi;                         \
    }

__global__ void __launch_bounds__(TB)
binsort_kernel(const float* __restrict__ pos,
               const float* __restrict__ pose,
               const float* __restrict__ intr,
               unsigned* __restrict__ bins,
               unsigned* __restrict__ histG,
               int n, int ppb, int region) {
    __shared__ unsigned h[NT];
    __shared__ unsigned base_[NT];
    __shared__ unsigned cur[NT];
    __shared__ unsigned sc[TB];

    int tid = threadIdx.x;
    for (int t = tid; t < NT; t += TB) h[t] = 0;
    __syncthreads();

    float r00 = pose[0], r01 = pose[1], r02 = pose[2],  t0 = pose[3];
    float r10 = pose[4], r11 = pose[5], r12 = pose[6],  t1 = pose[7];
    float r20 = pose[8], r21 = pose[9], r22 = pose[10], t2 = pose[11];
    float fx = intr[0], cx = intr[2];
    float fy = intr[4], cy = intr[5];

    int start = blockIdx.x * ppb;            // ppb multiple of 4
    int cnt = min(start + ppb, n) - start;   // multiple of 4 (n mult 4)
    if (cnt < 0) cnt = 0;

    const float4* p4 = (const float4*)(pos + (size_t)3 * (size_t)start);

    // ---- pass 1: project, histogram only (no stash) ----
    for (int j4 = tid * 4; j4 < cnt; j4 += TB * 4) {
        int g = j4 >> 2;
        float4 A = p4[3 * g + 0];
        float4 B = p4[3 * g + 1];
        float4 C = p4[3 * g + 2];
        unsigned pv[4];
        PROJ4(pv, A, B, C)
        #pragma unroll
        for (int k = 0; k < 4; ++k) {
            if (pv[k] != 0xFFFFFFFFu) {
                unsigned yi = pv[k] >> 10, xi = pv[k] & 1023u;
                atomicAdd(&h[((yi >> 5) << 5) + (xi >> 5)], 1u);   // LDS
            }
        }
    }
    __syncthreads();

    // ---- exclusive scan of RAW counts (thread owns tiles 2t, 2t+1) ----
    unsigned c0 = h[2 * tid];
    unsigned c1 = h[2 * tid + 1];
    unsigned v = c0 + c1;
    sc[tid] = v;
    __syncthreads();
    for (int off = 1; off < TB; off <<= 1) {
        unsigned add = (tid >= off) ? sc[tid - off] : 0u;
        __syncthreads();
        v += add;
        sc[tid] = v;
        __syncthreads();
    }
    base_[2 * tid]     = v - c0 - c1;
    base_[2 * tid + 1] = v - c1;
    __syncthreads();

    // ---- publish (base<<16 | count) TILE-MAJOR; init cursors ----
    for (int t = tid; t < NT; t += TB) {
        cur[t] = base_[t];
        histG[(size_t)t * NB + blockIdx.x] = (base_[t] << 16) | h[t];
    }
    __syncthreads();

    // ---- pass 2: RE-project (L3-resident) + scatter via LDS cursors ----
    unsigned* myRegion = bins + (size_t)blockIdx.x * (size_t)region;
    for (int j4 = tid * 4; j4 < cnt; j4 += TB * 4) {
        int g = j4 >> 2;
        float4 A = p4[3 * g + 0];
        float4 B = p4[3 * g + 1];
        float4 C = p4[3 * g + 2];
        unsigned pv[4];
        PROJ4(pv, A, B, C)
        #pragma unroll
        for (int k = 0; k < 4; ++k) {
            unsigned p = pv[k];
            if (p == 0xFFFFFFFFu) continue;
            unsigned xi = p & 1023u, yi = p >> 10;
            unsigned t  = ((yi >> 5) << 5) + (xi >> 5);
            unsigned lp = ((yi & 31u) << 5) + (xi & 31u);
            unsigned slot = atomicAdd(&cur[t], 1u);     // LDS
            myRegion[slot] = (lp << 22) | (unsigned)(start + j4 + k);
        }
    }
}

__global__ void __launch_bounds__(TB)
paint_kernel(const unsigned* __restrict__ bins,
             const unsigned* __restrict__ histG,
             const float* __restrict__ colors,
             float* __restrict__ out,
             int region) {
    __shared__ unsigned win[NT];    // winner index + 1 per local pixel
    int t = blockIdx.x;
    int tid = threadIdx.x;
    win[tid] = 0;
    win[tid + TB] = 0;
    __syncthreads();

    // thread tid owns run (region tid, tile t): exact count, dense
    {
        unsigned pk = histG[(size_t)t * NB + tid];      // coalesced
        unsigned sbase = pk >> 16, cnt = pk & 0xFFFFu;
        const unsigned* seg = bins + (size_t)tid * (size_t)region + sbase;
        for (unsigned k = 0; k < cnt; ++k) {
            unsigned e = seg[k];
            atomicMax(&win[e >> 22], (e & 0x3FFFFFu) + 1u); // LDS
        }
    }
    __syncthreads();

    int tx = (t & 31) << 5, ty = (t >> 5) << 5;
    for (int l = tid; l < NT; l += TB) {
        unsigned w = win[l];
        float r = 0.0f, g = 0.0f, bl = 0.0f;
        if (w) {
            unsigned wi = w - 1u;
            r  = fminf(fmaxf(colors[3 * wi + 0], 0.0f), 1.0f);
            g  = fminf(fmaxf(colors[3 * wi + 1], 0.0f), 1.0f);
            bl = fminf(fmaxf(colors[3 * wi + 2], 0.0f), 1.0f);
        }
        int x = tx + (l & 31), y = ty + (l >> 5);
        int p = y * IMGW + x;
        out[p] = r;
        out[IMGHW + p] = g;
        out[2 * IMGHW + p] = bl;
    }
}

// ---------- fallback: memset + single atomic pass + paint ----------

__global__ void proj_simple(const float* __restrict__ pos,
                            const float* __restrict__ pose,
                            const float* __restrict__ intr,
                            const int* __restrict__ Hp,
                            const int* __restrict__ Wp,
                            int* __restrict__ winner, int n) {
    int i = blockIdx.x * blockDim.x + threadIdx.x;
    if (i >= n) return;
    float px = pos[3 * i], py = pos[3 * i + 1], pz = pos[3 * i + 2];
    float x = pose[0] * px + pose[1] * py + pose[2]  * pz + pose[3];
    float y = pose[4] * px + pose[5] * py + pose[6]  * pz + pose[7];
    float z = pose[8] * px + pose[9] * py + pose[10] * pz + pose[11];
    float u = intr[0] * x / z + intr[2];
    float v = intr[4] * y / z + intr[5];
    int xi = (int)u, yi = (int)v;
    int W = *Wp, H = *Hp;
    if (xi >= 0 && xi < W && yi >= 0 && yi < H) atomicMax(&winner[yi * W + xi], i);
}

__global__ void paint_simple(const int* __restrict__ winner,
                             const float* __restrict__ colors,
                             float* __restrict__ out, int HW) {
    int p = blockIdx.x * blockDim.x + threadIdx.x;
    if (p >= HW) return;
    int w = winner[p];
    float r = 0.0f, g = 0.0f, b = 0.0f;
    if (w >= 0) {
        r = fminf(fmaxf(colors[3 * w + 0], 0.0f), 1.0f);
        g = fminf(fmaxf(colors[3 * w + 1], 0.0f), 1.0f);
        b = fminf(fmaxf(colors[3 * w + 2], 0.0f), 1.0f);
    }
    out[p] = r; out[HW + p] = g; out[2 * HW + p] = b;
}

extern "C" void kernel_launch(void* const* d_in, const int* in_sizes, int n_in,
                              void* d_out, int out_size, void* d_ws, size_t ws_size,
                              hipStream_t stream) {
    const float* positions = (const float*)d_in[0];
    const float* colors    = (const float*)d_in[1];
    const float* pose      = (const float*)d_in[2];
    const float* intr      = (const float*)d_in[3];
    const int*   Hp        = (const int*)d_in[4];
    const int*   Wp        = (const int*)d_in[5];
    float* out = (float*)d_out;

    int n  = in_sizes[0] / 3;       // number of points
    int HW = out_size / 3;          // H*W pixels

    int ppb = ((n + NB - 1) / NB + 3) & ~3;             // multiple of 4
    int region = (int)align8u((unsigned)ppb);           // dense, aligned base
    unsigned* bins  = (unsigned*)d_ws;
    unsigned* histG = bins + (size_t)NB * (size_t)region;
    size_t needFast = ((size_t)NB * region + (size_t)NT * NB) * sizeof(unsigned);

    // 16-bit run counts/bases in histG packs require ppb < 65536
    bool fast = (HW == IMGHW) && (n >= 4096) && ((n & 3) == 0) &&
                (ppb < 65536) && (n <= 4000000) && (ws_size >= needFast);

    if (fast) {
        binsort_kernel<<<NB, TB, 0, stream>>>(positions, pose, intr,
                                              bins, histG, n, ppb, region);
        paint_kernel<<<NT, TB, 0, stream>>>(bins, histG, colors, out, region);
        return;
    }

    // ---- fallback ----
    int* winner = (int*)d_ws;
    const int block = 256;
    hipMemsetAsync(winner, 0xFF, (size_t)HW * sizeof(int), stream);
    int grid = (n + block - 1) / block;
    proj_simple<<<grid, block, 0, stream>>>(positions, pose, intr, Hp, Wp,
                                            winner, n);
    int grid2 = (HW + block - 1) / block;
    paint_simple<<<grid2, block, 0, stream>>>(winner, colors, out, HW);
}